// Round 1
// 253.402 us; speedup vs baseline: 1.5102x; 1.5102x over previous
//
#include <hip/hip_runtime.h>

typedef unsigned short u16;
typedef __attribute__((ext_vector_type(8))) short short8;
typedef __attribute__((ext_vector_type(4))) float float4v;
typedef __attribute__((ext_vector_type(4))) int int4v;
typedef __attribute__((ext_vector_type(2))) int int2v;

#define EPS 1e-5f
#define NC 256
#define NT 251
#define NF 7
#define NSP 1757   // NF*NT
#define NB 32

// workspace layout (float offsets)
#define OFF_QEC 0
#define OFF_KEC 256
#define OFF_QEF 512
#define OFF_KEF 768
#define OFF_QET 1024
#define OFF_KET 1280
#define OFF_VSC 1536
#define OFF_VOF 1792
#define OFF_CONST 2048   // [0..5]=q/k consts c,f,t  [6]=s_c [7]=s_f [8]=s_t
#define OFF_DC 2064      // 256
#define OFF_DF 2320      // 256 (251 used)
#define OFF_DT 2576      // 16 (7 used)
#define WS_END 2592
// optional fused-t staging
#define OFF_QT 2592            // 32*251*7 -> padded 56320
#define OFF_KT (OFF_QT+56320)
#define WS2_END (OFF_KT+56320) // ~461 KB
// optional pre-tiled bf16 copy of v_w in MFMA LDS layout: u16[65536] = 32768 floats
#define OFF_WB16 WS2_END
#define WS3_END (WS2_END+32768) // ~592 KB

__device__ __forceinline__ u16 f2b(float f) {   // fp32 -> bf16 RNE
    unsigned int u = __float_as_uint(f);
    return (u16)((u + 0x7FFFu + ((u >> 16) & 1u)) >> 16);
}

// ---------------------------------------------------------------- prep
// blocks 0..23 : 6 matvecs x 4 output-tiles, 4-way split-K per block
// block 24     : v-branch scale/offset, lbn consts, bias consts, zero d-accums
// blocks 25..32: tile v_w into bf16 MFMA fragment layout (only if ws permits)
__global__ __launch_bounds__(256) void prep_kernel(
    const float* qc_w, const float* qc_bn, const float* kc_w, const float* kc_bn, const float* lc_bn,
    const float* qf_w, const float* qf_bn, const float* kf_w, const float* kf_bn, const float* lf_bn,
    const float* qt_w, const float* qt_bn, const float* kt_w, const float* kt_bn, const float* lt_bn,
    const float* v_b, const float* v_bn, const float* v_w, float* ws)
{
    int tid = threadIdx.x;
    int blk = blockIdx.x;
    __shared__ float sc[256];
    __shared__ float red[256];
    if (blk < 24) {
        int m = blk >> 2, j = blk & 3;
        const float* w; const float* bn; float* out; int O;
        switch (m) {
            case 0: w=qc_w; bn=qc_bn; out=ws+OFF_QEC; O=NT; break;
            case 1: w=kc_w; bn=kc_bn; out=ws+OFF_KEC; O=NT; break;
            case 2: w=qf_w; bn=qf_bn; out=ws+OFF_QEF; O=NC; break;
            case 3: w=kf_w; bn=kf_bn; out=ws+OFF_KEF; O=NC; break;
            case 4: w=qt_w; bn=qt_bn; out=ws+OFF_QET; O=NC; break;
            default: w=kt_w; bn=kt_bn; out=ws+OFF_KET; O=NC; break;
        }
        // phase A: per-row scale, computed once in parallel (was: rsqrtf inside the o-loop)
        if (tid < O) sc[tid] = bn[tid] * rsqrtf(bn[3*O+tid] + EPS);
        __syncthreads();
        // phase B: 64 outputs per block, 4-way split-K; pure fma loop -> loads pipeline
        int tl = tid & 63, kc4 = tid >> 6;
        int t = j*64 + tl;
        float acc = 0.f;
        if (t < O) {
            #pragma unroll 8
            for (int o = kc4; o < O; o += 4)
                acc = fmaf(sc[o], w[(size_t)o*O + t], acc);
        }
        red[tid] = acc;
        __syncthreads();
        if (tid < 64) {
            int tt = j*64 + tid;
            if (tt < O)
                out[tt] = (red[tid] + red[tid+64] + red[tid+128] + red[tid+192]) / (float)O;
        }
    } else if (blk == 24) {
        if (tid < NC) {
            float s = v_bn[tid] * rsqrtf(v_bn[3*NC+tid] + EPS);
            ws[OFF_VSC+tid] = s;
            ws[OFF_VOF+tid] = v_bn[NC+tid] - v_bn[2*NC+tid]*s + v_b[tid]*s;
        }
        if (tid == 0) {
            ws[OFF_CONST+6] = lc_bn[0] * rsqrtf(lc_bn[3] + EPS);
            ws[OFF_CONST+7] = lf_bn[0] * rsqrtf(lf_bn[3] + EPS);
            ws[OFF_CONST+8] = lt_bn[0] * rsqrtf(lt_bn[3] + EPS);
        }
        // zero the d accumulators (ws is poisoned every call)
        for (int i = tid; i < WS_END - OFF_DC; i += 256) ws[OFF_DC + i] = 0.f;
        // bias consts for the 6 matvec branches
        const float* bns[6] = {qc_bn, kc_bn, qf_bn, kf_bn, qt_bn, kt_bn};
        #pragma unroll
        for (int m2 = 0; m2 < 6; ++m2) {
            int O = (m2 < 2) ? NT : NC;
            const float* bn = bns[m2];
            float bs = 0.f;
            if (tid < O) {
                float s = bn[tid] * rsqrtf(bn[3*O+tid] + EPS);
                bs = bn[O+tid] - bn[2*O+tid]*s;
            }
            red[tid] = bs; __syncthreads();
            for (int s2 = 128; s2 > 0; s2 >>= 1) { if (tid < s2) red[tid] += red[tid+s2]; __syncthreads(); }
            if (tid == 0) ws[OFF_CONST+m2] = red[0] / (float)O;
            __syncthreads();
        }
    } else {
        // blocks 25..32: pre-tile v_w into bf16, exact MFMA LDS layout per (o_blk, k_step):
        // region r = o_blk*8 + ks (4096 u16 each); within: [frag(8)][kquad(4)][o16(16)][8k]
        u16* wb = (u16*)(ws + OFF_WB16);
        int base = (blk - 25) * 8192;
        for (int i = tid; i < 8192; i += 256) {
            int idx = base + i;
            int r = idx >> 12, q = idx & 4095;
            int o = ((r >> 3) << 7) + ((q >> 9) << 4) + ((q >> 3) & 15);
            int k = ((r & 7) << 5) + (((q >> 7) & 3) << 3) + (q & 7);
            wb[idx] = f2b(v_w[o*NC + k]);
        }
    }
}

// ------------ qv/kv for all branches + c/f diag softmax
// 512-thread blocks: threads 0..255 = ch-phase + c-softmax,
//                    threads 256..506 = t-phase + f-softmax (concurrent).
__global__ __launch_bounds__(512) void qkt_kernel(const float* __restrict__ x,
                                                  float* __restrict__ ws, int fuse_t)
{
    __shared__ float kvc[NC];
    __shared__ float kvf[NT];
    int tid = threadIdx.x;
    int n = blockIdx.x;
    int b = n / NF, f = n % NF;
    const float* xb = x + (size_t)b*NC*NSP + (size_t)f*NT;
    const float* cst = ws + OFF_CONST;

    float qc = 0.f, kc = 0.f, qf = 0.f, kf = 0.f;

    if (tid < 256) {
        // thread == ch, reduce over t (row-major stream)
        const float* xrow = xb + (size_t)tid*NSP;
        const float* qeC = ws + OFF_QEC;  const float* keC = ws + OFF_KEC;
        #pragma unroll 16
        for (int t = 0; t < NT; ++t) {
            float xv = xrow[t];
            qc = fmaf(qeC[t], xv, qc);
            kc = fmaf(keC[t], xv, kc);
        }
        qc += cst[0]; kc += cst[1];
        kvc[tid] = kc;
    } else if (tid - 256 < NT) {
        // thread == t, reduce over ch (coalesced lanes along t)
        int t = tid - 256;
        const float* xc = xb + t;
        const float* qeF = ws + OFF_QEF;  const float* keF = ws + OFF_KEF;
        const float* qeT = ws + OFF_QET;  const float* keT = ws + OFF_KET;
        float qt = 0.f, kt = 0.f;
        #pragma unroll 8
        for (int ch = 0; ch < NC; ++ch) {
            float xv = xc[(size_t)ch*NSP];
            qf = fmaf(qeF[ch], xv, qf);
            kf = fmaf(keF[ch], xv, kf);
            qt = fmaf(qeT[ch], xv, qt);
            kt = fmaf(keT[ch], xv, kt);
        }
        qf += cst[2]; kf += cst[3];
        qt += cst[4]; kt += cst[5];
        kvf[t] = kf;
        if (fuse_t) {
            ws[OFF_QT + ((size_t)b*NT + t)*NF + f] = qt;
            ws[OFF_KT + ((size_t)b*NT + t)*NF + f] = kt;
        }
    }
    __syncthreads();

    if (tid < 256) {
        // c diag softmax (4 accumulators: break fmax/add dep chains, pipeline LDS reads)
        float s = cst[6];
        float qi = s * qc;
        float m0=-1e30f, m1=-1e30f, m2=-1e30f, m3=-1e30f;
        #pragma unroll 2
        for (int jj = 0; jj < NC; jj += 4) {
            m0 = fmaxf(m0, qi*kvc[jj]);
            m1 = fmaxf(m1, qi*kvc[jj+1]);
            m2 = fmaxf(m2, qi*kvc[jj+2]);
            m3 = fmaxf(m3, qi*kvc[jj+3]);
        }
        float m = fmaxf(fmaxf(m0,m1), fmaxf(m2,m3));
        float d0=0.f, d1=0.f, d2=0.f, d3=0.f;
        #pragma unroll 2
        for (int jj = 0; jj < NC; jj += 4) {
            d0 += __expf(qi*kvc[jj]   - m);
            d1 += __expf(qi*kvc[jj+1] - m);
            d2 += __expf(qi*kvc[jj+2] - m);
            d3 += __expf(qi*kvc[jj+3] - m);
        }
        float den = (d0+d1)+(d2+d3);
        atomicAdd(&ws[OFF_DC + tid], __expf(qi*kc - m)/den);
    } else if (tid - 256 < NT) {
        int t = tid - 256;
        float s = cst[7];
        float qi = s * qf;
        float m0=-1e30f, m1=-1e30f, m2=-1e30f, m3=-1e30f;
        int jj = 0;
        #pragma unroll 2
        for (; jj + 3 < NT; jj += 4) {
            m0 = fmaxf(m0, qi*kvf[jj]);
            m1 = fmaxf(m1, qi*kvf[jj+1]);
            m2 = fmaxf(m2, qi*kvf[jj+2]);
            m3 = fmaxf(m3, qi*kvf[jj+3]);
        }
        for (; jj < NT; ++jj) m0 = fmaxf(m0, qi*kvf[jj]);
        float m = fmaxf(fmaxf(m0,m1), fmaxf(m2,m3));
        float d0=0.f, d1=0.f, d2=0.f, d3=0.f;
        jj = 0;
        #pragma unroll 2
        for (; jj + 3 < NT; jj += 4) {
            d0 += __expf(qi*kvf[jj]   - m);
            d1 += __expf(qi*kvf[jj+1] - m);
            d2 += __expf(qi*kvf[jj+2] - m);
            d3 += __expf(qi*kvf[jj+3] - m);
        }
        for (; jj < NT; ++jj) d0 += __expf(qi*kvf[jj] - m);
        float den = (d0+d1)+(d2+d3);
        atomicAdd(&ws[OFF_DF + t], __expf(qi*kf - m)/den);
    }
}

// --------------------- t diag softmax from staged qt/kt (fused path)
__global__ __launch_bounds__(256) void tsm_kernel(float* __restrict__ ws)
{
    __shared__ float dt_acc[NF];
    int tid = threadIdx.x, b = blockIdx.x;
    if (tid < NF) dt_acc[tid] = 0.f;
    __syncthreads();
    if (tid < NT) {
        float s = ws[OFF_CONST+8];
        const float* qp = ws + OFF_QT + ((size_t)b*NT + tid)*NF;
        const float* kp = ws + OFF_KT + ((size_t)b*NT + tid)*NF;
        float q[NF], k[NF];
        #pragma unroll
        for (int i = 0; i < NF; ++i) { q[i] = qp[i]; k[i] = kp[i]; }
        #pragma unroll
        for (int i = 0; i < NF; ++i) {
            float qi = s * q[i];
            float m = -1e30f;
            #pragma unroll
            for (int j = 0; j < NF; ++j) m = fmaxf(m, qi*k[j]);
            float den = 0.f;
            #pragma unroll
            for (int j = 0; j < NF; ++j) den += __expf(qi*k[j] - m);
            atomicAdd(&dt_acc[i], __expf(qi*k[i] - m)/den);
        }
    }
    __syncthreads();
    if (tid < NF) atomicAdd(&ws[OFF_DT + tid], dt_acc[tid]);
}

// --------------------- t-branch fallback (re-reads x; used if ws too small)
__global__ __launch_bounds__(256) void t_kernel(const float* __restrict__ x, float* __restrict__ ws)
{
    __shared__ float qs[32*NF], ks[32*NF], dt_acc[NF];
    int tid = threadIdx.x;
    int b  = blockIdx.x >> 3;
    int t0 = (blockIdx.x & 7) * 32;
    int tl = tid & 31, fr = tid >> 5;
    int t = t0 + tl;
    bool act = (fr < NF) && (t < NT);
    if (tid < NF) dt_acc[tid] = 0.f;

    float aq = 0.f, ak = 0.f;
    const float* qeT = ws + OFF_QET;
    const float* keT = ws + OFF_KET;
    if (act) {
        const float* xr = x + (size_t)b*NC*NSP + fr*NT + t;
        #pragma unroll 8
        for (int ch = 0; ch < NC; ++ch) {
            float xv = xr[(size_t)ch*NSP];
            aq = fmaf(qeT[ch], xv, aq);
            ak = fmaf(keT[ch], xv, ak);
        }
    }
    __syncthreads();
    if (act) {
        qs[tl*NF + fr] = aq + ws[OFF_CONST+4];
        ks[tl*NF + fr] = ak + ws[OFF_CONST+5];
    }
    __syncthreads();
    if (act) {
        float s = ws[OFF_CONST+8];
        float qi = s * qs[tl*NF + fr];
        float m = -1e30f;
        #pragma unroll
        for (int j = 0; j < NF; ++j) m = fmaxf(m, qi*ks[tl*NF + j]);
        float den = 0.f;
        #pragma unroll
        for (int j = 0; j < NF; ++j) den += __expf(qi*ks[tl*NF + j] - m);
        atomicAdd(&dt_acc[fr], __expf(qi*ks[tl*NF + fr] - m)/den);
    }
    __syncthreads();
    if (tid < NF) atomicAdd(&ws[OFF_DT + tid], dt_acc[tid]);
}

// --------------------- main GEMM (v branch) via bf16 MFMA + fused epilogue
// X in LDS as k-pair-packed u32 [kg=k/4][n(128)][pair]: B-fragment = 2x ds_read_b64
// (was 8x ds_read_u16). W: if WBF, copied from pre-tiled bf16 (no per-block f2b).
template<int WBF>
__global__ __launch_bounds__(256) void main_kernel(
    const float* __restrict__ x, const float* __restrict__ vw,
    const float* __restrict__ ws, float* __restrict__ out)
{
    __shared__ u16 Ws[8*512];           // 8 KB   [frag][kquad][o16][8k]
    __shared__ unsigned int Xs[8*256];  // 8 KB   [kg][n][pair]
    __shared__ float vsL[128], voL[128], dcL[128], dtfL[128];

    int tid = threadIdx.x;
    int n0 = blockIdx.x * 128;
    int o0 = blockIdx.y * 128;
    int b  = blockIdx.z;
    const size_t xbase = (size_t)b * NC * NSP;

    if (tid < 128) {
        int o = o0 + tid;
        vsL[tid] = ws[OFF_VSC+o];
        voL[tid] = ws[OFF_VOF+o];
        dcL[tid] = ws[OFF_DC+o];
        int nn = n0 + tid; if (nn > NSP-1) nn = NSP-1;
        int ff = nn / NT, tt = nn - ff*NT;
        dtfL[tid] = ws[OFF_DT+ff] + ws[OFF_DF+tt];
    }

    int wv = tid >> 6, ln = tid & 63;
    int quad = ln >> 4, l16 = ln & 15;
    int wr = wv >> 1, wc = wv & 1;

    float4v acc[4][4] = {};

    int kgs = tid >> 5, nbs = tid & 31;   // X staging: 8 kg-groups x 32 col-groups
    int oo = tid >> 1, half = tid & 1;    // legacy W staging mapping

    const u16* wbg = nullptr;
    if constexpr (WBF) wbg = (const u16*)(ws + OFF_WB16) + (size_t)blockIdx.y * 32768;

    for (int ks = 0; ks < 8; ++ks) {
        int k0 = ks * 32;
        if constexpr (WBF) {
            // straight 16B copies: pre-tiled bf16 already in fragment order
            const int4v* wsrc = (const int4v*)(wbg + (size_t)ks*4096);
            *(int4v*)&Ws[tid*8]        = wsrc[tid];
            *(int4v*)&Ws[2048 + tid*8] = wsrc[256 + tid];
        } else {
            const float* wr4 = vw + (size_t)(o0+oo)*NC + k0 + half*16;
            union { u16 us[16]; short8 v[2]; } wb;
            #pragma unroll
            for (int c = 0; c < 16; ++c) wb.us[c] = f2b(wr4[c]);
            int frg = oo >> 4, o16 = oo & 15;
            #pragma unroll
            for (int qq = 0; qq < 2; ++qq) {
                int qd = 2*half + qq;
                *(short8*)&Ws[frg*512 + qd*128 + o16*8] = wb.v[qq];
            }
        }
        {
            // X tile 32k x 128n: thread loads 4 rows x 4 cols, packs k-pairs
            int nbase = n0 + nbs*4;
            const float* xr = x + xbase + (size_t)(k0 + kgs*4)*NSP + nbase;
            float xv[4][4];
            if (nbase + 3 < NSP) {
                #pragma unroll
                for (int rr = 0; rr < 4; ++rr)
                    #pragma unroll
                    for (int i = 0; i < 4; ++i)
                        xv[rr][i] = xr[(size_t)rr*NSP + i];
            } else {
                #pragma unroll
                for (int rr = 0; rr < 4; ++rr)
                    #pragma unroll
                    for (int i = 0; i < 4; ++i)
                        xv[rr][i] = (nbase + i < NSP) ? xr[(size_t)rr*NSP + i] : 0.f;
            }
            unsigned int pk[8];
            #pragma unroll
            for (int i = 0; i < 4; ++i)
                #pragma unroll
                for (int jp = 0; jp < 2; ++jp)
                    pk[i*2+jp] = (unsigned int)f2b(xv[2*jp][i])
                               | ((unsigned int)f2b(xv[2*jp+1][i]) << 16);
            *(int4v*)&Xs[kgs*256 + nbs*8]     = *(int4v*)&pk[0];
            *(int4v*)&Xs[kgs*256 + nbs*8 + 4] = *(int4v*)&pk[4];
        }
        __syncthreads();

        short8 afr[4], bfr[4];
        #pragma unroll
        for (int fr = 0; fr < 4; ++fr)
            afr[fr] = *(short8*)&Ws[(wr*4+fr)*512 + ln*8];
        #pragma unroll
        for (int fc = 0; fc < 4; ++fc) {
            int nn = wc*64 + fc*16 + l16;
            int2v lo = *(int2v*)&Xs[(2*quad)*256 + nn*2];
            int2v hi = *(int2v*)&Xs[(2*quad+1)*256 + nn*2];
            union { int i4[4]; short8 v; } u;
            u.i4[0] = lo.x; u.i4[1] = lo.y; u.i4[2] = hi.x; u.i4[3] = hi.y;
            bfr[fc] = u.v;
        }
        #pragma unroll
        for (int fr = 0; fr < 4; ++fr)
            #pragma unroll
            for (int fc = 0; fc < 4; ++fc)
                acc[fr][fc] = __builtin_amdgcn_mfma_f32_16x16x32_bf16(
                    afr[fr], bfr[fc], acc[fr][fc], 0, 0, 0);
        __syncthreads();
    }

    #pragma unroll
    for (int fr = 0; fr < 4; ++fr) {
        #pragma unroll
        for (int r = 0; r < 4; ++r) {
            int ol = wr*64 + fr*16 + quad*4 + r;
            int o = o0 + ol;
            float vs = vsL[ol], vo = voL[ol], dcv = dcL[ol];
            const size_t orow = xbase + (size_t)o*NSP;
            #pragma unroll
            for (int fc = 0; fc < 4; ++fc) {
                int nl = wc*64 + fc*16 + l16;
                int nn = n0 + nl;
                if (nn < NSP) {
                    size_t gi = orow + nn;
                    out[gi] = (acc[fr][fc][r]*vs + vo)*(dcv + dtfL[nl]) + x[gi];
                }
            }
        }
    }
}

extern "C" void kernel_launch(void* const* d_in, const int* in_sizes, int n_in,
                              void* d_out, int out_size, void* d_ws, size_t ws_size,
                              hipStream_t stream)
{
    const float* x    = (const float*)d_in[0];
    const float* qc_w = (const float*)d_in[1];  const float* qc_bn = (const float*)d_in[2];
    const float* kc_w = (const float*)d_in[3];  const float* kc_bn = (const float*)d_in[4];
    const float* lc_bn= (const float*)d_in[5];
    const float* qf_w = (const float*)d_in[6];  const float* qf_bn = (const float*)d_in[7];
    const float* kf_w = (const float*)d_in[8];  const float* kf_bn = (const float*)d_in[9];
    const float* lf_bn= (const float*)d_in[10];
    const float* qt_w = (const float*)d_in[11]; const float* qt_bn = (const float*)d_in[12];
    const float* kt_w = (const float*)d_in[13]; const float* kt_bn = (const float*)d_in[14];
    const float* lt_bn= (const float*)d_in[15];
    const float* v_w  = (const float*)d_in[16]; const float* v_b   = (const float*)d_in[17];
    const float* v_bn = (const float*)d_in[18];
    float* ws = (float*)d_ws;
    float* out = (float*)d_out;

    int fuse_t = (ws_size >= (size_t)WS2_END * sizeof(float)) ? 1 : 0;
    int wbf    = (ws_size >= (size_t)WS3_END * sizeof(float)) ? 1 : 0;

    prep_kernel<<<wbf ? 33 : 25, 256, 0, stream>>>(qc_w,qc_bn,kc_w,kc_bn,lc_bn,
                                                   qf_w,qf_bn,kf_w,kf_bn,lf_bn,
                                                   qt_w,qt_bn,kt_w,kt_bn,lt_bn,
                                                   v_b,v_bn,v_w,ws);
    qkt_kernel<<<NB*NF, 512, 0, stream>>>(x, ws, fuse_t);
    if (fuse_t) tsm_kernel<<<NB, 256, 0, stream>>>(ws);
    else        t_kernel<<<NB*8, 256, 0, stream>>>(x, ws);
    if (wbf) main_kernel<1><<<dim3(14, 2, NB), 256, 0, stream>>>(x, v_w, ws, out);
    else     main_kernel<0><<<dim3(14, 2, NB), 256, 0, stream>>>(x, v_w, ws, out);
}

// Round 2
// 245.475 us; speedup vs baseline: 1.5590x; 1.0323x over previous
//
#include <hip/hip_runtime.h>

typedef unsigned short u16;
typedef __attribute__((ext_vector_type(8))) short short8;
typedef __attribute__((ext_vector_type(4))) float float4v;
typedef __attribute__((ext_vector_type(4))) int int4v;
typedef __attribute__((ext_vector_type(2))) int int2v;

#define EPS 1e-5f
#define NC 256
#define NT 251
#define NF 7
#define NSP 1757   // NF*NT
#define NB 32

// workspace layout (float offsets)
#define OFF_QEC 0
#define OFF_KEC 256
#define OFF_QEF 512
#define OFF_KEF 768
#define OFF_QET 1024
#define OFF_KET 1280
#define OFF_VSC 1536
#define OFF_VOF 1792
#define OFF_CONST 2048   // [0..5]=q/k consts c,f,t  [6]=s_c [7]=s_f [8]=s_t
#define OFF_DC 2064      // 256
#define OFF_DF 2320      // 256 (251 used)
#define OFF_DT 2576      // 16 (7 used)
#define WS_END 2592
// optional fused-t staging
#define OFF_QT 2592            // 32*251*7 -> padded 56320
#define OFF_KT (OFF_QT+56320)
#define WS2_END (OFF_KT+56320) // ~461 KB
// optional pre-tiled bf16 copy of v_w in MFMA LDS layout: u16[65536] = 32768 floats
#define OFF_WB16 WS2_END
#define WS3_END (WS2_END+32768) // ~592 KB

// Xs swizzle: word-in-row w (0..255 u32), row kg (0..7). XOR bits 3..4 with kg>>1
// -> the 4 quads of the b64 fragment read land on different bank sets (4-way -> 2-way).
#define XSW(kg, w) ((kg)*256 + ((w) ^ ((((kg)>>1)&3)<<3)))

__device__ __forceinline__ u16 f2b(float f) {   // fp32 -> bf16 RNE
    unsigned int u = __float_as_uint(f);
    return (u16)((u + 0x7FFFu + ((u >> 16) & 1u)) >> 16);
}

// ---------------------------------------------------------------- prep
// blocks 0..23 : 6 matvecs x 4 output-tiles, 4-way split-K; j==0 blocks also do bias const
// block 24     : v-branch scale/offset, lbn consts, zero d-accums
// blocks 25..32: tile v_w into bf16 MFMA fragment layout (only if ws permits)
__global__ __launch_bounds__(256) void prep_kernel(
    const float* qc_w, const float* qc_bn, const float* kc_w, const float* kc_bn, const float* lc_bn,
    const float* qf_w, const float* qf_bn, const float* kf_w, const float* kf_bn, const float* lf_bn,
    const float* qt_w, const float* qt_bn, const float* kt_w, const float* kt_bn, const float* lt_bn,
    const float* v_b, const float* v_bn, const float* v_w, float* ws)
{
    int tid = threadIdx.x;
    int blk = blockIdx.x;
    __shared__ float sc[256];
    __shared__ float red[256];
    if (blk < 24) {
        int m = blk >> 2, j = blk & 3;
        const float* w; const float* bn; float* out; int O;
        switch (m) {
            case 0: w=qc_w; bn=qc_bn; out=ws+OFF_QEC; O=NT; break;
            case 1: w=kc_w; bn=kc_bn; out=ws+OFF_KEC; O=NT; break;
            case 2: w=qf_w; bn=qf_bn; out=ws+OFF_QEF; O=NC; break;
            case 3: w=kf_w; bn=kf_bn; out=ws+OFF_KEF; O=NC; break;
            case 4: w=qt_w; bn=qt_bn; out=ws+OFF_QET; O=NC; break;
            default: w=kt_w; bn=kt_bn; out=ws+OFF_KET; O=NC; break;
        }
        if (tid < O) sc[tid] = bn[tid] * rsqrtf(bn[3*O+tid] + EPS);
        __syncthreads();
        int tl = tid & 63, kc4 = tid >> 6;
        int t = j*64 + tl;
        float acc = 0.f;
        if (t < O) {
            #pragma unroll 8
            for (int o = kc4; o < O; o += 4)
                acc = fmaf(sc[o], w[(size_t)o*O + t], acc);
        }
        red[tid] = acc;
        __syncthreads();
        if (tid < 64) {
            int tt = j*64 + tid;
            if (tt < O)
                out[tt] = (red[tid] + red[tid+64] + red[tid+128] + red[tid+192]) / (float)O;
        }
        if (j == 0) {   // bias const for this branch, in parallel with other blocks
            float bs = 0.f;
            if (tid < O) bs = bn[O+tid] - bn[2*O+tid]*sc[tid];
            __syncthreads();
            red[tid] = bs; __syncthreads();
            for (int s2 = 128; s2 > 0; s2 >>= 1) { if (tid < s2) red[tid] += red[tid+s2]; __syncthreads(); }
            if (tid == 0) ws[OFF_CONST+m] = red[0] / (float)O;
        }
    } else if (blk == 24) {
        if (tid < NC) {
            float s = v_bn[tid] * rsqrtf(v_bn[3*NC+tid] + EPS);
            ws[OFF_VSC+tid] = s;
            ws[OFF_VOF+tid] = v_bn[NC+tid] - v_bn[2*NC+tid]*s + v_b[tid]*s;
        }
        if (tid == 0) {
            ws[OFF_CONST+6] = lc_bn[0] * rsqrtf(lc_bn[3] + EPS);
            ws[OFF_CONST+7] = lf_bn[0] * rsqrtf(lf_bn[3] + EPS);
            ws[OFF_CONST+8] = lt_bn[0] * rsqrtf(lt_bn[3] + EPS);
        }
        for (int i = tid; i < WS_END - OFF_DC; i += 256) ws[OFF_DC + i] = 0.f;
    } else {
        // blocks 25..32: pre-tile v_w into bf16, exact MFMA LDS layout per (o_blk, k_step)
        u16* wb = (u16*)(ws + OFF_WB16);
        int base = (blk - 25) * 8192;
        for (int i = tid; i < 8192; i += 256) {
            int idx = base + i;
            int r = idx >> 12, q = idx & 4095;
            int o = ((r >> 3) << 7) + ((q >> 9) << 4) + ((q >> 3) & 15);
            int k = ((r & 7) << 5) + (((q >> 7) & 3) << 3) + (q & 7);
            wb[idx] = f2b(v_w[o*NC + k]);
        }
    }
}

// ------------ qv/kv + diag softmax, split into independent role-blocks:
// block (n, role): role 0 = c-branch (reduce over t), role 1 = f/t-branch (reduce over ch)
// 512 threads; 2-way split of the reduction axis per role.
__global__ __launch_bounds__(512) void qkt_kernel(const float* __restrict__ x,
                                                  float* __restrict__ ws, int fuse_t)
{
    __shared__ float kv[NC];
    __shared__ float p0[512], p1[512], p2[512], p3[512];
    int tid = threadIdx.x;
    int bid = blockIdx.x;
    int n = bid >> 1, role = bid & 1;
    int b = n / NF, f = n % NF;
    const float* xb = x + (size_t)b*NC*NSP + (size_t)f*NT;
    const float* cst = ws + OFF_CONST;
    int half = tid >> 8, lid = tid & 255;

    if (role == 0) {
        // ---- c-branch: thread == ch, 2-way split over t
        const float* xrow = xb + (size_t)lid*NSP;
        const float* qeC = ws + OFF_QEC;  const float* keC = ws + OFF_KEC;
        float qc = 0.f, kc = 0.f;
        int t0 = half ? 126 : 0, t1 = half ? NT : 126;
        #pragma unroll 16
        for (int t = t0; t < t1; ++t) {
            float xv = xrow[t];
            qc = fmaf(qeC[t], xv, qc);
            kc = fmaf(keC[t], xv, kc);
        }
        p0[tid] = qc; p1[tid] = kc;
        __syncthreads();
        if (tid < 256) {
            qc = p0[tid] + p0[tid+256] + cst[0];
            kc = p1[tid] + p1[tid+256] + cst[1];
            kv[tid] = kc;
        }
        __syncthreads();
        if (tid < 256) {
            float s = cst[6];
            float qi = s * qc;
            float m0=-1e30f, m1=-1e30f, m2=-1e30f, m3=-1e30f;
            #pragma unroll 2
            for (int jj = 0; jj < NC; jj += 4) {
                m0 = fmaxf(m0, qi*kv[jj]);
                m1 = fmaxf(m1, qi*kv[jj+1]);
                m2 = fmaxf(m2, qi*kv[jj+2]);
                m3 = fmaxf(m3, qi*kv[jj+3]);
            }
            float m = fmaxf(fmaxf(m0,m1), fmaxf(m2,m3));
            float d0=0.f, d1=0.f, d2=0.f, d3=0.f;
            #pragma unroll 2
            for (int jj = 0; jj < NC; jj += 4) {
                d0 += __expf(qi*kv[jj]   - m);
                d1 += __expf(qi*kv[jj+1] - m);
                d2 += __expf(qi*kv[jj+2] - m);
                d3 += __expf(qi*kv[jj+3] - m);
            }
            float den = (d0+d1)+(d2+d3);
            atomicAdd(&ws[OFF_DC + tid], __expf(qi*kv[tid] - m)/den);
        }
    } else {
        // ---- f/t-branch: thread == t, 2-way split over ch
        float qf=0.f, kf=0.f, qt=0.f, kt=0.f;
        if (lid < NT) {
            const float* xc = xb + lid + (size_t)(half*128)*NSP;
            const float* qeF = ws + OFF_QEF + half*128;  const float* keF = ws + OFF_KEF + half*128;
            const float* qeT = ws + OFF_QET + half*128;  const float* keT = ws + OFF_KET + half*128;
            #pragma unroll 8
            for (int ch = 0; ch < 128; ++ch) {
                float xv = xc[(size_t)ch*NSP];
                qf = fmaf(qeF[ch], xv, qf);
                kf = fmaf(keF[ch], xv, kf);
                qt = fmaf(qeT[ch], xv, qt);
                kt = fmaf(keT[ch], xv, kt);
            }
        }
        p0[tid]=qf; p1[tid]=kf; p2[tid]=qt; p3[tid]=kt;
        __syncthreads();
        float qfv=0.f, kfv=0.f;
        if (tid < NT) {
            qfv = p0[tid] + p0[tid+256] + cst[2];
            kfv = p1[tid] + p1[tid+256] + cst[3];
            float qtv = p2[tid] + p2[tid+256] + cst[4];
            float ktv = p3[tid] + p3[tid+256] + cst[5];
            kv[tid] = kfv;
            if (fuse_t) {
                ws[OFF_QT + ((size_t)b*NT + tid)*NF + f] = qtv;
                ws[OFF_KT + ((size_t)b*NT + tid)*NF + f] = ktv;
            }
        }
        __syncthreads();
        if (tid < NT) {
            float s = cst[7];
            float qi = s * qfv;
            float m0=-1e30f, m1=-1e30f, m2=-1e30f, m3=-1e30f;
            int jj = 0;
            #pragma unroll 2
            for (; jj + 3 < NT; jj += 4) {
                m0 = fmaxf(m0, qi*kv[jj]);
                m1 = fmaxf(m1, qi*kv[jj+1]);
                m2 = fmaxf(m2, qi*kv[jj+2]);
                m3 = fmaxf(m3, qi*kv[jj+3]);
            }
            for (; jj < NT; ++jj) m0 = fmaxf(m0, qi*kv[jj]);
            float m = fmaxf(fmaxf(m0,m1), fmaxf(m2,m3));
            float d0=0.f, d1=0.f, d2=0.f, d3=0.f;
            jj = 0;
            #pragma unroll 2
            for (; jj + 3 < NT; jj += 4) {
                d0 += __expf(qi*kv[jj]   - m);
                d1 += __expf(qi*kv[jj+1] - m);
                d2 += __expf(qi*kv[jj+2] - m);
                d3 += __expf(qi*kv[jj+3] - m);
            }
            for (; jj < NT; ++jj) d0 += __expf(qi*kv[jj] - m);
            float den = (d0+d1)+(d2+d3);
            atomicAdd(&ws[OFF_DF + tid], __expf(qi*kfv - m)/den);
        }
    }
}

// --------------------- t diag softmax from staged qt/kt (fused path)
__global__ __launch_bounds__(256) void tsm_kernel(float* __restrict__ ws)
{
    __shared__ float dt_acc[NF];
    int tid = threadIdx.x, b = blockIdx.x;
    if (tid < NF) dt_acc[tid] = 0.f;
    __syncthreads();
    if (tid < NT) {
        float s = ws[OFF_CONST+8];
        const float* qp = ws + OFF_QT + ((size_t)b*NT + tid)*NF;
        const float* kp = ws + OFF_KT + ((size_t)b*NT + tid)*NF;
        float q[NF], k[NF];
        #pragma unroll
        for (int i = 0; i < NF; ++i) { q[i] = qp[i]; k[i] = kp[i]; }
        #pragma unroll
        for (int i = 0; i < NF; ++i) {
            float qi = s * q[i];
            float m = -1e30f;
            #pragma unroll
            for (int j = 0; j < NF; ++j) m = fmaxf(m, qi*k[j]);
            float den = 0.f;
            #pragma unroll
            for (int j = 0; j < NF; ++j) den += __expf(qi*k[j] - m);
            atomicAdd(&dt_acc[i], __expf(qi*k[i] - m)/den);
        }
    }
    __syncthreads();
    if (tid < NF) atomicAdd(&ws[OFF_DT + tid], dt_acc[tid]);
}

// --------------------- t-branch fallback (re-reads x; used if ws too small)
__global__ __launch_bounds__(256) void t_kernel(const float* __restrict__ x, float* __restrict__ ws)
{
    __shared__ float qs[32*NF], ks[32*NF], dt_acc[NF];
    int tid = threadIdx.x;
    int b  = blockIdx.x >> 3;
    int t0 = (blockIdx.x & 7) * 32;
    int tl = tid & 31, fr = tid >> 5;
    int t = t0 + tl;
    bool act = (fr < NF) && (t < NT);
    if (tid < NF) dt_acc[tid] = 0.f;

    float aq = 0.f, ak = 0.f;
    const float* qeT = ws + OFF_QET;
    const float* keT = ws + OFF_KET;
    if (act) {
        const float* xr = x + (size_t)b*NC*NSP + fr*NT + t;
        #pragma unroll 8
        for (int ch = 0; ch < NC; ++ch) {
            float xv = xr[(size_t)ch*NSP];
            aq = fmaf(qeT[ch], xv, aq);
            ak = fmaf(keT[ch], xv, ak);
        }
    }
    __syncthreads();
    if (act) {
        qs[tl*NF + fr] = aq + ws[OFF_CONST+4];
        ks[tl*NF + fr] = ak + ws[OFF_CONST+5];
    }
    __syncthreads();
    if (act) {
        float s = ws[OFF_CONST+8];
        float qi = s * qs[tl*NF + fr];
        float m = -1e30f;
        #pragma unroll
        for (int j = 0; j < NF; ++j) m = fmaxf(m, qi*ks[tl*NF + j]);
        float den = 0.f;
        #pragma unroll
        for (int j = 0; j < NF; ++j) den += __expf(qi*ks[tl*NF + j] - m);
        atomicAdd(&dt_acc[fr], __expf(qi*ks[tl*NF + fr] - m)/den);
    }
    __syncthreads();
    if (tid < NF) atomicAdd(&ws[OFF_DT + tid], dt_acc[tid]);
}

// --------------------- main GEMM (v branch): double-buffered, software-pipelined
// 1-D grid of 896; XCD-aware decode pairs both o-tiles of an (n,b) tile on one XCD.
template<int WBF>
__global__ __launch_bounds__(256) void main_kernel(
    const float* __restrict__ x, const float* __restrict__ vw,
    const float* __restrict__ ws, float* __restrict__ out)
{
    __shared__ u16 Ws[2][4096];           // 16 KB  [buf][frag(8)][kquad(4)][o16(16)][8k]
    __shared__ unsigned int Xs[2][2048];  // 16 KB  [buf][kg(8)][n(128)][pair] (swizzled)
    __shared__ float vsL[128], voL[128], dcL[128], dtfL[128];

    int tid = threadIdx.x;
    // XCD-aware decode: blockIdx.x%8 = XCD (round-robin dispatch). Give each XCD a
    // contiguous chunk of 56 (n,b) tiles; consecutive in-XCD ids = the 2 o-tiles of a pair.
    int flat = blockIdx.x;                 // 0..895
    int xcd = flat & 7, idx = flat >> 3;   // idx 0..111
    int pair = xcd*56 + (idx >> 1);        // 0..447
    int o0 = (idx & 1) * 128;
    int n0 = (pair % 14) * 128;
    int b  = pair / 14;
    const size_t xbase = (size_t)b * NC * NSP;

    if (tid < 128) {
        int o = o0 + tid;
        vsL[tid] = ws[OFF_VSC+o];
        voL[tid] = ws[OFF_VOF+o];
        dcL[tid] = ws[OFF_DC+o];
        int nn = n0 + tid; if (nn > NSP-1) nn = NSP-1;
        int ff = nn / NT, tt = nn - ff*NT;
        dtfL[tid] = ws[OFF_DT+ff] + ws[OFF_DF+tt];
    }

    int wv = tid >> 6, ln = tid & 63;
    int quad = ln >> 4, l16 = ln & 15;
    int wr = wv >> 1, wc = wv & 1;

    float4v acc[4][4] = {};

    int kgs = tid >> 5, nbs = tid & 31;   // X staging: 8 kg-groups x 32 col-groups
    int oo = tid >> 1, half = tid & 1;    // W staging mapping (non-WBF)

    const u16* wbg = nullptr;
    if constexpr (WBF) wbg = (const u16*)(ws + OFF_WB16) + (size_t)(o0 >> 7) * 32768;

    // prefetch registers
    int4v wA, wB;                 // WBF path
    float wf[16];                 // non-WBF path
    float xv[4][4];

    auto loadW = [&](int ks) {
        if constexpr (WBF) {
            const int4v* wsrc = (const int4v*)(wbg + (size_t)ks*4096);
            wA = wsrc[tid]; wB = wsrc[256 + tid];
        } else {
            const float* wr4 = vw + (size_t)(o0+oo)*NC + ks*32 + half*16;
            #pragma unroll
            for (int c = 0; c < 16; ++c) wf[c] = wr4[c];
        }
    };
    auto loadX = [&](int ks) {
        int nbase = n0 + nbs*4;
        const float* xr = x + xbase + (size_t)(ks*32 + kgs*4)*NSP + nbase;
        if (nbase + 3 < NSP) {
            #pragma unroll
            for (int rr = 0; rr < 4; ++rr)
                #pragma unroll
                for (int i = 0; i < 4; ++i)
                    xv[rr][i] = xr[(size_t)rr*NSP + i];
        } else {
            #pragma unroll
            for (int rr = 0; rr < 4; ++rr)
                #pragma unroll
                for (int i = 0; i < 4; ++i)
                    xv[rr][i] = (nbase + i < NSP) ? xr[(size_t)rr*NSP + i] : 0.f;
        }
    };
    auto storeWX = [&](int bufi) {
        if constexpr (WBF) {
            *(int4v*)&Ws[bufi][tid*8]        = wA;
            *(int4v*)&Ws[bufi][2048 + tid*8] = wB;
        } else {
            union { u16 us[16]; short8 v[2]; } wb;
            #pragma unroll
            for (int c = 0; c < 16; ++c) wb.us[c] = f2b(wf[c]);
            int frg = oo >> 4, o16 = oo & 15;
            #pragma unroll
            for (int qq = 0; qq < 2; ++qq) {
                int qd = 2*half + qq;
                *(short8*)&Ws[bufi][frg*512 + qd*128 + o16*8] = wb.v[qq];
            }
        }
        unsigned int pk[8];
        #pragma unroll
        for (int i = 0; i < 4; ++i)
            #pragma unroll
            for (int jp = 0; jp < 2; ++jp)
                pk[i*2+jp] = (unsigned int)f2b(xv[2*jp][i])
                           | ((unsigned int)f2b(xv[2*jp+1][i]) << 16);
        *(int4v*)&Xs[bufi][XSW(kgs, nbs*8)]     = *(int4v*)&pk[0];
        *(int4v*)&Xs[bufi][XSW(kgs, nbs*8 + 4)] = *(int4v*)&pk[4];
    };

    // prologue: stage ks=0 into buf0
    loadW(0); loadX(0);
    storeWX(0);
    __syncthreads();

    for (int ks = 0; ks < 8; ++ks) {
        int cur = ks & 1;
        if (ks < 7) { loadW(ks+1); loadX(ks+1); }   // issue next-step loads (in flight)

        short8 afr[4], bfr[4];
        #pragma unroll
        for (int fr = 0; fr < 4; ++fr)
            afr[fr] = *(short8*)&Ws[cur][(wr*4+fr)*512 + ln*8];
        #pragma unroll
        for (int fc = 0; fc < 4; ++fc) {
            int nn = wc*64 + fc*16 + l16;
            int2v lo = *(int2v*)&Xs[cur][XSW(2*quad,   2*nn)];
            int2v hi = *(int2v*)&Xs[cur][XSW(2*quad+1, 2*nn)];
            union { int i4[4]; short8 v; } u;
            u.i4[0] = lo.x; u.i4[1] = lo.y; u.i4[2] = hi.x; u.i4[3] = hi.y;
            bfr[fc] = u.v;
        }
        #pragma unroll
        for (int fr = 0; fr < 4; ++fr)
            #pragma unroll
            for (int fc = 0; fc < 4; ++fc)
                acc[fr][fc] = __builtin_amdgcn_mfma_f32_16x16x32_bf16(
                    afr[fr], bfr[fc], acc[fr][fc], 0, 0, 0);

        if (ks < 7) storeWX(cur ^ 1);               // convert + write next buffer
        __syncthreads();
    }

    #pragma unroll
    for (int fr = 0; fr < 4; ++fr) {
        #pragma unroll
        for (int r = 0; r < 4; ++r) {
            int ol = wr*64 + fr*16 + quad*4 + r;
            int o = o0 + ol;
            float vs = vsL[ol], vo = voL[ol], dcv = dcL[ol];
            const size_t orow = xbase + (size_t)o*NSP;
            #pragma unroll
            for (int fc = 0; fc < 4; ++fc) {
                int nl = wc*64 + fc*16 + l16;
                int nn = n0 + nl;
                if (nn < NSP) {
                    size_t gi = orow + nn;
                    out[gi] = (acc[fr][fc][r]*vs + vo)*(dcv + dtfL[nl]) + x[gi];
                }
            }
        }
    }
}

extern "C" void kernel_launch(void* const* d_in, const int* in_sizes, int n_in,
                              void* d_out, int out_size, void* d_ws, size_t ws_size,
                              hipStream_t stream)
{
    const float* x    = (const float*)d_in[0];
    const float* qc_w = (const float*)d_in[1];  const float* qc_bn = (const float*)d_in[2];
    const float* kc_w = (const float*)d_in[3];  const float* kc_bn = (const float*)d_in[4];
    const float* lc_bn= (const float*)d_in[5];
    const float* qf_w = (const float*)d_in[6];  const float* qf_bn = (const float*)d_in[7];
    const float* kf_w = (const float*)d_in[8];  const float* kf_bn = (const float*)d_in[9];
    const float* lf_bn= (const float*)d_in[10];
    const float* qt_w = (const float*)d_in[11]; const float* qt_bn = (const float*)d_in[12];
    const float* kt_w = (const float*)d_in[13]; const float* kt_bn = (const float*)d_in[14];
    const float* lt_bn= (const float*)d_in[15];
    const float* v_w  = (const float*)d_in[16]; const float* v_b   = (const float*)d_in[17];
    const float* v_bn = (const float*)d_in[18];
    float* ws = (float*)d_ws;
    float* out = (float*)d_out;

    int fuse_t = (ws_size >= (size_t)WS2_END * sizeof(float)) ? 1 : 0;
    int wbf    = (ws_size >= (size_t)WS3_END * sizeof(float)) ? 1 : 0;

    prep_kernel<<<wbf ? 33 : 25, 256, 0, stream>>>(qc_w,qc_bn,kc_w,kc_bn,lc_bn,
                                                   qf_w,qf_bn,kf_w,kf_bn,lf_bn,
                                                   qt_w,qt_bn,kt_w,kt_bn,lt_bn,
                                                   v_b,v_bn,v_w,ws);
    qkt_kernel<<<NB*NF*2, 512, 0, stream>>>(x, ws, fuse_t);
    if (fuse_t) tsm_kernel<<<NB, 256, 0, stream>>>(ws);
    else        t_kernel<<<NB*8, 256, 0, stream>>>(x, ws);
    if (wbf) main_kernel<1><<<896, 256, 0, stream>>>(x, v_w, ws, out);
    else     main_kernel<0><<<896, 256, 0, stream>>>(x, v_w, ws, out);
}

// Round 3
// 220.194 us; speedup vs baseline: 1.7380x; 1.1148x over previous
//
#include <hip/hip_runtime.h>

typedef unsigned short u16;
typedef __attribute__((ext_vector_type(8))) short short8;
typedef __attribute__((ext_vector_type(4))) float float4v;
typedef __attribute__((ext_vector_type(4))) int int4v;
typedef __attribute__((ext_vector_type(2))) int int2v;

#define EPS 1e-5f
#define NC 256
#define NT 251
#define NF 7
#define NSP 1757   // NF*NT
#define NB 32

// workspace layout (float offsets)
#define OFF_QEC 0
#define OFF_KEC 256
#define OFF_QEF 512
#define OFF_KEF 768
#define OFF_QET 1024
#define OFF_KET 1280
#define OFF_VSC 1536
#define OFF_VOF 1792
#define OFF_CONST 2048   // [0..5]=q/k consts c,f,t  [6]=s_c [7]=s_f [8]=s_t
#define OFF_DC 2064      // 256
#define OFF_DF 2320      // 256 (251 used)
#define OFF_DT 2576      // 16 (7 used)
#define WS_END 2592
// fused-t staging (old layout [b][t][f] for fallback; new path uses [b][sp])
#define OFF_QT 2592            // 56320
#define OFF_KT (OFF_QT+56320)  // 56320
#define WS2_END (OFF_KT+56320) // 115232 floats
// pre-tiled bf16 v_w in MFMA LDS layout
#define OFF_WB16 WS2_END
#define WS3_END (WS2_END+32768) // 148000 floats
// new-path staging: qf/kf [b][sp], qc/kc [n][ch]
#define OFF_QF2 WS3_END              // 56320
#define OFF_KF2 (OFF_QF2+56320)      // 56320
#define OFF_QCS (OFF_KF2+56320)      // 57344
#define OFF_KCS (OFF_QCS+57344)      // 57344
#define WS4_END (OFF_KCS+57344)      // 375328 floats ≈ 1.43 MB

// Xs swizzle for main_kernel (4-way -> 2-way on b64 frag reads)
#define XSW(kg, w) ((kg)*256 + ((w) ^ ((((kg)>>1)&3)<<3)))

__device__ __forceinline__ u16 f2b(float f) {   // fp32 -> bf16 RNE
    unsigned int u = __float_as_uint(f);
    return (u16)((u + 0x7FFFu + ((u >> 16) & 1u)) >> 16);
}

// ---------------------------------------------------------------- prep
__global__ __launch_bounds__(256) void prep_kernel(
    const float* qc_w, const float* qc_bn, const float* kc_w, const float* kc_bn, const float* lc_bn,
    const float* qf_w, const float* qf_bn, const float* kf_w, const float* kf_bn, const float* lf_bn,
    const float* qt_w, const float* qt_bn, const float* kt_w, const float* kt_bn, const float* lt_bn,
    const float* v_b, const float* v_bn, const float* v_w, float* ws)
{
    int tid = threadIdx.x;
    int blk = blockIdx.x;
    __shared__ float sc[256];
    __shared__ float red[256];
    if (blk < 24) {
        int m = blk >> 2, j = blk & 3;
        const float* w; const float* bn; float* out; int O;
        switch (m) {
            case 0: w=qc_w; bn=qc_bn; out=ws+OFF_QEC; O=NT; break;
            case 1: w=kc_w; bn=kc_bn; out=ws+OFF_KEC; O=NT; break;
            case 2: w=qf_w; bn=qf_bn; out=ws+OFF_QEF; O=NC; break;
            case 3: w=kf_w; bn=kf_bn; out=ws+OFF_KEF; O=NC; break;
            case 4: w=qt_w; bn=qt_bn; out=ws+OFF_QET; O=NC; break;
            default: w=kt_w; bn=kt_bn; out=ws+OFF_KET; O=NC; break;
        }
        if (tid < O) sc[tid] = bn[tid] * rsqrtf(bn[3*O+tid] + EPS);
        __syncthreads();
        int tl = tid & 63, kc4 = tid >> 6;
        int t = j*64 + tl;
        float acc = 0.f;
        if (t < O) {
            #pragma unroll 8
            for (int o = kc4; o < O; o += 4)
                acc = fmaf(sc[o], w[(size_t)o*O + t], acc);
        }
        red[tid] = acc;
        __syncthreads();
        if (tid < 64) {
            int tt = j*64 + tid;
            if (tt < O)
                out[tt] = (red[tid] + red[tid+64] + red[tid+128] + red[tid+192]) / (float)O;
        }
        if (j == 0) {
            float bs = 0.f;
            if (tid < O) bs = bn[O+tid] - bn[2*O+tid]*sc[tid];
            __syncthreads();
            red[tid] = bs; __syncthreads();
            for (int s2 = 128; s2 > 0; s2 >>= 1) { if (tid < s2) red[tid] += red[tid+s2]; __syncthreads(); }
            if (tid == 0) ws[OFF_CONST+m] = red[0] / (float)O;
        }
    } else if (blk == 24) {
        if (tid < NC) {
            float s = v_bn[tid] * rsqrtf(v_bn[3*NC+tid] + EPS);
            ws[OFF_VSC+tid] = s;
            ws[OFF_VOF+tid] = v_bn[NC+tid] - v_bn[2*NC+tid]*s + v_b[tid]*s;
        }
        if (tid == 0) {
            ws[OFF_CONST+6] = lc_bn[0] * rsqrtf(lc_bn[3] + EPS);
            ws[OFF_CONST+7] = lf_bn[0] * rsqrtf(lf_bn[3] + EPS);
            ws[OFF_CONST+8] = lt_bn[0] * rsqrtf(lt_bn[3] + EPS);
        }
        for (int i = tid; i < WS_END - OFF_DC; i += 256) ws[OFF_DC + i] = 0.f;
    } else {
        // blocks 25..32: tile v_w -> bf16 MFMA layout. COALESCED float4 reads,
        // scattered 8B writes (stores don't stall the wave).
        u16* wb = (u16*)(ws + OFF_WB16);
        int base = (blk - 25) * 8192;   // elements of v_w
        for (int i4 = tid; i4 < 2048; i4 += 256) {
            int e = base + i4*4;
            int o = e >> 8, k = e & 255;
            float4v v = *(const float4v*)(v_w + e);
            u16 h0 = f2b(v.x), h1 = f2b(v.y), h2 = f2b(v.z), h3 = f2b(v.w);
            int r = ((o>>7)<<3) | (k>>5);
            int q = (((o>>4)&7)<<9) | (((k>>3)&3)<<7) | ((o&15)<<3) | (k&7);
            unsigned long long pk = (unsigned long long)h0 | ((unsigned long long)h1<<16)
                                  | ((unsigned long long)h2<<32) | ((unsigned long long)h3<<48);
            *(unsigned long long*)&wb[(r<<12) | q] = pk;
        }
    }
}

// --------------- qv/kv computation, fully parallel, staged to ws (new path)
// blocks 0..1791  : c-part. (n, 32ch-tile): stage x tile in LDS coalesced,
//                   row-reduce from LDS, 16-lane shfl tree. -> QCS/KCS
// blocks 1792..2239: ft-part. (b, 128sp-chunk): 16-way ch split, 4 sp/thread.
//                   -> QF2/KF2 and QT/KT (new [b][sp] layout), consts added.
__global__ __launch_bounds__(512) void qv_kernel(const float* __restrict__ x,
                                                 float* __restrict__ ws)
{
    __shared__ float lds[8608];
    int tid = threadIdx.x;
    int blk = blockIdx.x;
    const float* cst = ws + OFF_CONST;

    if (blk < 1792) {
        // ---------- c-part ----------
        int n = blk >> 3, cb = blk & 7;
        int b = n / NF, f = n % NF;
        const float* xb = x + (size_t)b*NC*NSP + (size_t)f*NT + (size_t)(cb*32)*NSP;
        // stage qeC/keC at 8096 / 8352
        if (tid < NT) lds[8096+tid] = ws[OFF_QEC+tid];
        else if (tid >= 256 && tid < 256+NT) lds[8352+tid-256] = ws[OFF_KEC+tid-256];
        // stage tile [32][253] rows, 2 rows per iter, coalesced
        int lr = tid >> 8, lane = tid & 255;
        #pragma unroll 4
        for (int i = 0; i < 16; ++i) {
            int r = 2*i + lr;
            if (lane < NT) lds[r*253 + lane] = xb[(size_t)r*NSP + lane];
        }
        __syncthreads();
        int r = tid >> 4, q = tid & 15;
        float qa = 0.f, ka = 0.f;
        #pragma unroll
        for (int i = 0; i < 16; ++i) {
            int t = q + 16*i;
            if (t < NT) {
                float xv = lds[r*253 + t];
                qa = fmaf(lds[8096+t], xv, qa);
                ka = fmaf(lds[8352+t], xv, ka);
            }
        }
        qa += __shfl_xor(qa, 1);  ka += __shfl_xor(ka, 1);
        qa += __shfl_xor(qa, 2);  ka += __shfl_xor(ka, 2);
        qa += __shfl_xor(qa, 4);  ka += __shfl_xor(ka, 4);
        qa += __shfl_xor(qa, 8);  ka += __shfl_xor(ka, 8);
        if (q == 0) {
            int ch = cb*32 + r;
            ws[OFF_QCS + n*256 + ch] = qa;
            ws[OFF_KCS + n*256 + ch] = ka;
        }
    } else {
        // ---------- ft-part ----------
        int fb = blk - 1792;             // 0..447
        int b = fb / 14, nchunk = fb % 14;
        int n0 = nchunk * 128;
        int spg = tid & 31, chg = tid >> 5;   // 32 sp-groups x 16 ch-groups
        // stage the 4 e-vectors at 5120/5376/5632/5888
        if (tid < 256) { lds[5120+tid] = ws[OFF_QEF+tid]; lds[5632+tid] = ws[OFF_QET+tid]; }
        else { int u = tid-256; lds[5376+u] = ws[OFF_KEF+u]; lds[5888+u] = ws[OFF_KET+u]; }
        __syncthreads();
        const size_t xbase = (size_t)b*NC*NSP;
        int sp0 = n0 + spg*4;
        bool full = (sp0 + 3 < NSP);
        float qf[4]={0,0,0,0}, kf[4]={0,0,0,0}, qt[4]={0,0,0,0}, kt[4]={0,0,0,0};
        #pragma unroll 4
        for (int i = 0; i < 16; ++i) {
            int ch = chg*16 + i;
            const float* xr = x + xbase + (size_t)ch*NSP + sp0;
            float xv[4];
            if (full) {
                xv[0]=xr[0]; xv[1]=xr[1]; xv[2]=xr[2]; xv[3]=xr[3];
            } else {
                #pragma unroll
                for (int j = 0; j < 4; ++j) xv[j] = (sp0+j < NSP) ? xr[j] : 0.f;
            }
            float eqf = lds[5120+ch], ekf = lds[5376+ch];
            float eqt = lds[5632+ch], ekt = lds[5888+ch];
            #pragma unroll
            for (int j = 0; j < 4; ++j) {
                qf[j] = fmaf(eqf, xv[j], qf[j]);
                kf[j] = fmaf(ekf, xv[j], kf[j]);
                qt[j] = fmaf(eqt, xv[j], qt[j]);
                kt[j] = fmaf(ekt, xv[j], kt[j]);
            }
        }
        // fold chg-pairs across wave halves (lanes 0-31 <-> 32-63)
        #pragma unroll
        for (int j = 0; j < 4; ++j) {
            qf[j] += __shfl_xor(qf[j], 32);
            kf[j] += __shfl_xor(kf[j], 32);
            qt[j] += __shfl_xor(qt[j], 32);
            kt[j] += __shfl_xor(kt[j], 32);
        }
        int wv = tid >> 6, ln = tid & 63;
        if (ln < 32) {
            int base = wv*640 + ln*20;      // region [0..5119], disjoint from e-vectors
            #pragma unroll
            for (int j = 0; j < 4; ++j) {
                lds[base+j]    = qf[j];
                lds[base+4+j]  = kf[j];
                lds[base+8+j]  = qt[j];
                lds[base+12+j] = kt[j];
            }
        }
        __syncthreads();
        if (tid < 32) {
            float acc[16];
            #pragma unroll
            for (int j = 0; j < 16; ++j) acc[j] = 0.f;
            #pragma unroll
            for (int w = 0; w < 8; ++w) {
                int base = w*640 + tid*20;
                #pragma unroll
                for (int j = 0; j < 16; ++j) acc[j] += lds[base+j];
            }
            int sp0w = n0 + tid*4;
            #pragma unroll
            for (int j = 0; j < 4; ++j) {
                if (sp0w + j < NSP) {
                    size_t o = (size_t)b*1760 + sp0w + j;
                    ws[OFF_QF2 + o] = acc[j]    + cst[2];
                    ws[OFF_KF2 + o] = acc[4+j]  + cst[3];
                    ws[OFF_QT  + o] = acc[8+j]  + cst[4];
                    ws[OFF_KT  + o] = acc[12+j] + cst[5];
                }
            }
        }
    }
}

// --------------- all three diag softmaxes from staged q/k (new path)
// blocks 0..223: (b,f): c-softmax (256) + f-softmax (251)
// blocks 224..255: per-b t-softmax (7x7 per t, summed over t)
__global__ __launch_bounds__(256) void sm_kernel(float* __restrict__ ws)
{
    __shared__ float kv[NC];
    __shared__ float kv2[NT];
    __shared__ float dt_acc[NF];
    int tid = threadIdx.x, blk = blockIdx.x;
    const float* cst = ws + OFF_CONST;

    if (blk < 224) {
        int b = blk / NF, f = blk % NF;
        float qcv = ws[OFF_QCS + blk*256 + tid] + cst[0];
        float kcv = ws[OFF_KCS + blk*256 + tid] + cst[1];
        kv[tid] = kcv;
        float qfv = 0.f, kfv = 0.f;
        if (tid < NT) {
            size_t o = (size_t)b*1760 + f*NT + tid;
            qfv = ws[OFF_QF2 + o];
            kfv = ws[OFF_KF2 + o];
            kv2[tid] = kfv;
        }
        __syncthreads();
        {   // c diag softmax
            float s = cst[6];
            float qi = s * qcv;
            float m0=-1e30f, m1=-1e30f, m2=-1e30f, m3=-1e30f;
            #pragma unroll 2
            for (int jj = 0; jj < NC; jj += 4) {
                m0 = fmaxf(m0, qi*kv[jj]);
                m1 = fmaxf(m1, qi*kv[jj+1]);
                m2 = fmaxf(m2, qi*kv[jj+2]);
                m3 = fmaxf(m3, qi*kv[jj+3]);
            }
            float m = fmaxf(fmaxf(m0,m1), fmaxf(m2,m3));
            float d0=0.f, d1=0.f, d2=0.f, d3=0.f;
            #pragma unroll 2
            for (int jj = 0; jj < NC; jj += 4) {
                d0 += __expf(qi*kv[jj]   - m);
                d1 += __expf(qi*kv[jj+1] - m);
                d2 += __expf(qi*kv[jj+2] - m);
                d3 += __expf(qi*kv[jj+3] - m);
            }
            float den = (d0+d1)+(d2+d3);
            atomicAdd(&ws[OFF_DC + tid], __expf(qi*kcv - m)/den);
        }
        if (tid < NT) {   // f diag softmax
            float s = cst[7];
            float qi = s * qfv;
            float m0=-1e30f, m1=-1e30f, m2=-1e30f, m3=-1e30f;
            int jj = 0;
            #pragma unroll 2
            for (; jj + 3 < NT; jj += 4) {
                m0 = fmaxf(m0, qi*kv2[jj]);
                m1 = fmaxf(m1, qi*kv2[jj+1]);
                m2 = fmaxf(m2, qi*kv2[jj+2]);
                m3 = fmaxf(m3, qi*kv2[jj+3]);
            }
            for (; jj < NT; ++jj) m0 = fmaxf(m0, qi*kv2[jj]);
            float m = fmaxf(fmaxf(m0,m1), fmaxf(m2,m3));
            float d0=0.f, d1=0.f, d2=0.f, d3=0.f;
            jj = 0;
            #pragma unroll 2
            for (; jj + 3 < NT; jj += 4) {
                d0 += __expf(qi*kv2[jj]   - m);
                d1 += __expf(qi*kv2[jj+1] - m);
                d2 += __expf(qi*kv2[jj+2] - m);
                d3 += __expf(qi*kv2[jj+3] - m);
            }
            for (; jj < NT; ++jj) d0 += __expf(qi*kv2[jj] - m);
            float den = (d0+d1)+(d2+d3);
            atomicAdd(&ws[OFF_DF + tid], __expf(qi*kfv - m)/den);
        }
    } else {
        int b = blk - 224;
        if (tid < NF) dt_acc[tid] = 0.f;
        __syncthreads();
        if (tid < NT) {
            float s = cst[8];
            float q[NF], k[NF];
            #pragma unroll
            for (int i = 0; i < NF; ++i) {
                size_t o = (size_t)b*1760 + i*NT + tid;
                q[i] = ws[OFF_QT + o];
                k[i] = ws[OFF_KT + o];
            }
            #pragma unroll
            for (int i = 0; i < NF; ++i) {
                float qi = s * q[i];
                float m = -1e30f;
                #pragma unroll
                for (int j = 0; j < NF; ++j) m = fmaxf(m, qi*k[j]);
                float den = 0.f;
                #pragma unroll
                for (int j = 0; j < NF; ++j) den += __expf(qi*k[j] - m);
                atomicAdd(&dt_acc[i], __expf(qi*k[i] - m)/den);
            }
        }
        __syncthreads();
        if (tid < NF) atomicAdd(&ws[OFF_DT + tid], dt_acc[tid]);
    }
}

// ------------ OLD-PATH kernels (fallback when ws too small) ------------
__global__ __launch_bounds__(512) void qkt_kernel(const float* __restrict__ x,
                                                  float* __restrict__ ws, int fuse_t)
{
    __shared__ float kv[NC];
    __shared__ float p0[512], p1[512], p2[512], p3[512];
    int tid = threadIdx.x;
    int bid = blockIdx.x;
    int n = bid >> 1, role = bid & 1;
    int b = n / NF, f = n % NF;
    const float* xb = x + (size_t)b*NC*NSP + (size_t)f*NT;
    const float* cst = ws + OFF_CONST;
    int half = tid >> 8, lid = tid & 255;

    if (role == 0) {
        const float* xrow = xb + (size_t)lid*NSP;
        const float* qeC = ws + OFF_QEC;  const float* keC = ws + OFF_KEC;
        float qc = 0.f, kc = 0.f;
        int t0 = half ? 126 : 0, t1 = half ? NT : 126;
        #pragma unroll 16
        for (int t = t0; t < t1; ++t) {
            float xv = xrow[t];
            qc = fmaf(qeC[t], xv, qc);
            kc = fmaf(keC[t], xv, kc);
        }
        p0[tid] = qc; p1[tid] = kc;
        __syncthreads();
        if (tid < 256) {
            qc = p0[tid] + p0[tid+256] + cst[0];
            kc = p1[tid] + p1[tid+256] + cst[1];
            kv[tid] = kc;
        }
        __syncthreads();
        if (tid < 256) {
            float s = cst[6];
            float qi = s * qc;
            float m0=-1e30f, m1=-1e30f, m2=-1e30f, m3=-1e30f;
            #pragma unroll 2
            for (int jj = 0; jj < NC; jj += 4) {
                m0 = fmaxf(m0, qi*kv[jj]);
                m1 = fmaxf(m1, qi*kv[jj+1]);
                m2 = fmaxf(m2, qi*kv[jj+2]);
                m3 = fmaxf(m3, qi*kv[jj+3]);
            }
            float m = fmaxf(fmaxf(m0,m1), fmaxf(m2,m3));
            float d0=0.f, d1=0.f, d2=0.f, d3=0.f;
            #pragma unroll 2
            for (int jj = 0; jj < NC; jj += 4) {
                d0 += __expf(qi*kv[jj]   - m);
                d1 += __expf(qi*kv[jj+1] - m);
                d2 += __expf(qi*kv[jj+2] - m);
                d3 += __expf(qi*kv[jj+3] - m);
            }
            float den = (d0+d1)+(d2+d3);
            atomicAdd(&ws[OFF_DC + tid], __expf(qi*kv[tid] - m)/den);
        }
    } else {
        float qf=0.f, kf=0.f, qt=0.f, kt=0.f;
        if (lid < NT) {
            const float* xc = xb + lid + (size_t)(half*128)*NSP;
            const float* qeF = ws + OFF_QEF + half*128;  const float* keF = ws + OFF_KEF + half*128;
            const float* qeT = ws + OFF_QET + half*128;  const float* keT = ws + OFF_KET + half*128;
            #pragma unroll 8
            for (int ch = 0; ch < 128; ++ch) {
                float xv = xc[(size_t)ch*NSP];
                qf = fmaf(qeF[ch], xv, qf);
                kf = fmaf(keF[ch], xv, kf);
                qt = fmaf(qeT[ch], xv, qt);
                kt = fmaf(keT[ch], xv, kt);
            }
        }
        p0[tid]=qf; p1[tid]=kf; p2[tid]=qt; p3[tid]=kt;
        __syncthreads();
        float qfv=0.f, kfv=0.f;
        if (tid < NT) {
            qfv = p0[tid] + p0[tid+256] + cst[2];
            kfv = p1[tid] + p1[tid+256] + cst[3];
            float qtv = p2[tid] + p2[tid+256] + cst[4];
            float ktv = p3[tid] + p3[tid+256] + cst[5];
            kv[tid] = kfv;
            if (fuse_t) {
                ws[OFF_QT + ((size_t)b*NT + tid)*NF + f] = qtv;
                ws[OFF_KT + ((size_t)b*NT + tid)*NF + f] = ktv;
            }
        }
        __syncthreads();
        if (tid < NT) {
            float s = cst[7];
            float qi = s * qfv;
            float m0=-1e30f, m1=-1e30f, m2=-1e30f, m3=-1e30f;
            int jj = 0;
            #pragma unroll 2
            for (; jj + 3 < NT; jj += 4) {
                m0 = fmaxf(m0, qi*kv[jj]);
                m1 = fmaxf(m1, qi*kv[jj+1]);
                m2 = fmaxf(m2, qi*kv[jj+2]);
                m3 = fmaxf(m3, qi*kv[jj+3]);
            }
            for (; jj < NT; ++jj) m0 = fmaxf(m0, qi*kv[jj]);
            float m = fmaxf(fmaxf(m0,m1), fmaxf(m2,m3));
            float d0=0.f, d1=0.f, d2=0.f, d3=0.f;
            jj = 0;
            #pragma unroll 2
            for (; jj + 3 < NT; jj += 4) {
                d0 += __expf(qi*kv[jj]   - m);
                d1 += __expf(qi*kv[jj+1] - m);
                d2 += __expf(qi*kv[jj+2] - m);
                d3 += __expf(qi*kv[jj+3] - m);
            }
            for (; jj < NT; ++jj) d0 += __expf(qi*kv[jj] - m);
            float den = (d0+d1)+(d2+d3);
            atomicAdd(&ws[OFF_DF + tid], __expf(qi*kfv - m)/den);
        }
    }
}

__global__ __launch_bounds__(256) void tsm_kernel(float* __restrict__ ws)
{
    __shared__ float dt_acc[NF];
    int tid = threadIdx.x, b = blockIdx.x;
    if (tid < NF) dt_acc[tid] = 0.f;
    __syncthreads();
    if (tid < NT) {
        float s = ws[OFF_CONST+8];
        const float* qp = ws + OFF_QT + ((size_t)b*NT + tid)*NF;
        const float* kp = ws + OFF_KT + ((size_t)b*NT + tid)*NF;
        float q[NF], k[NF];
        #pragma unroll
        for (int i = 0; i < NF; ++i) { q[i] = qp[i]; k[i] = kp[i]; }
        #pragma unroll
        for (int i = 0; i < NF; ++i) {
            float qi = s * q[i];
            float m = -1e30f;
            #pragma unroll
            for (int j = 0; j < NF; ++j) m = fmaxf(m, qi*k[j]);
            float den = 0.f;
            #pragma unroll
            for (int j = 0; j < NF; ++j) den += __expf(qi*k[j] - m);
            atomicAdd(&dt_acc[i], __expf(qi*k[i] - m)/den);
        }
    }
    __syncthreads();
    if (tid < NF) atomicAdd(&ws[OFF_DT + tid], dt_acc[tid]);
}

__global__ __launch_bounds__(256) void t_kernel(const float* __restrict__ x, float* __restrict__ ws)
{
    __shared__ float qs[32*NF], ks[32*NF], dt_acc[NF];
    int tid = threadIdx.x;
    int b  = blockIdx.x >> 3;
    int t0 = (blockIdx.x & 7) * 32;
    int tl = tid & 31, fr = tid >> 5;
    int t = t0 + tl;
    bool act = (fr < NF) && (t < NT);
    if (tid < NF) dt_acc[tid] = 0.f;

    float aq = 0.f, ak = 0.f;
    const float* qeT = ws + OFF_QET;
    const float* keT = ws + OFF_KET;
    if (act) {
        const float* xr = x + (size_t)b*NC*NSP + fr*NT + t;
        #pragma unroll 8
        for (int ch = 0; ch < NC; ++ch) {
            float xv = xr[(size_t)ch*NSP];
            aq = fmaf(qeT[ch], xv, aq);
            ak = fmaf(keT[ch], xv, ak);
        }
    }
    __syncthreads();
    if (act) {
        qs[tl*NF + fr] = aq + ws[OFF_CONST+4];
        ks[tl*NF + fr] = ak + ws[OFF_CONST+5];
    }
    __syncthreads();
    if (act) {
        float s = ws[OFF_CONST+8];
        float qi = s * qs[tl*NF + fr];
        float m = -1e30f;
        #pragma unroll
        for (int j = 0; j < NF; ++j) m = fmaxf(m, qi*ks[tl*NF + j]);
        float den = 0.f;
        #pragma unroll
        for (int j = 0; j < NF; ++j) den += __expf(qi*ks[tl*NF + j] - m);
        atomicAdd(&dt_acc[fr], __expf(qi*ks[tl*NF + fr] - m)/den);
    }
    __syncthreads();
    if (tid < NF) atomicAdd(&ws[OFF_DT + tid], dt_acc[tid]);
}

// --------------------- main GEMM (v branch): double-buffered, software-pipelined
template<int WBF>
__global__ __launch_bounds__(256) void main_kernel(
    const float* __restrict__ x, const float* __restrict__ vw,
    const float* __restrict__ ws, float* __restrict__ out)
{
    __shared__ u16 Ws[2][4096];
    __shared__ unsigned int Xs[2][2048];
    __shared__ float vsL[128], voL[128], dcL[128], dtfL[128];

    int tid = threadIdx.x;
    int flat = blockIdx.x;                 // 0..895
    int xcd = flat & 7, idx = flat >> 3;   // idx 0..111
    int pair = xcd*56 + (idx >> 1);        // 0..447
    int o0 = (idx & 1) * 128;
    int n0 = (pair % 14) * 128;
    int b  = pair / 14;
    const size_t xbase = (size_t)b * NC * NSP;

    if (tid < 128) {
        int o = o0 + tid;
        vsL[tid] = ws[OFF_VSC+o];
        voL[tid] = ws[OFF_VOF+o];
        dcL[tid] = ws[OFF_DC+o];
        int nn = n0 + tid; if (nn > NSP-1) nn = NSP-1;
        int ff = nn / NT, tt = nn - ff*NT;
        dtfL[tid] = ws[OFF_DT+ff] + ws[OFF_DF+tt];
    }

    int wv = tid >> 6, ln = tid & 63;
    int quad = ln >> 4, l16 = ln & 15;
    int wr = wv >> 1, wc = wv & 1;

    float4v acc[4][4] = {};

    int kgs = tid >> 5, nbs = tid & 31;
    int oo = tid >> 1, half = tid & 1;

    const u16* wbg = nullptr;
    if constexpr (WBF) wbg = (const u16*)(ws + OFF_WB16) + (size_t)(o0 >> 7) * 32768;

    int4v wA, wB;
    float wf[16];
    float xv[4][4];

    auto loadW = [&](int ks) {
        if constexpr (WBF) {
            const int4v* wsrc = (const int4v*)(wbg + (size_t)ks*4096);
            wA = wsrc[tid]; wB = wsrc[256 + tid];
        } else {
            const float* wr4 = vw + (size_t)(o0+oo)*NC + ks*32 + half*16;
            #pragma unroll
            for (int c = 0; c < 16; ++c) wf[c] = wr4[c];
        }
    };
    auto loadX = [&](int ks) {
        int nbase = n0 + nbs*4;
        const float* xr = x + xbase + (size_t)(ks*32 + kgs*4)*NSP + nbase;
        if (nbase + 3 < NSP) {
            #pragma unroll
            for (int rr = 0; rr < 4; ++rr)
                #pragma unroll
                for (int i = 0; i < 4; ++i)
                    xv[rr][i] = xr[(size_t)rr*NSP + i];
        } else {
            #pragma unroll
            for (int rr = 0; rr < 4; ++rr)
                #pragma unroll
                for (int i = 0; i < 4; ++i)
                    xv[rr][i] = (nbase + i < NSP) ? xr[(size_t)rr*NSP + i] : 0.f;
        }
    };
    auto storeWX = [&](int bufi) {
        if constexpr (WBF) {
            *(int4v*)&Ws[bufi][tid*8]        = wA;
            *(int4v*)&Ws[bufi][2048 + tid*8] = wB;
        } else {
            union { u16 us[16]; short8 v[2]; } wb;
            #pragma unroll
            for (int c = 0; c < 16; ++c) wb.us[c] = f2b(wf[c]);
            int frg = oo >> 4, o16 = oo & 15;
            #pragma unroll
            for (int qq = 0; qq < 2; ++qq) {
                int qd = 2*half + qq;
                *(short8*)&Ws[bufi][frg*512 + qd*128 + o16*8] = wb.v[qq];
            }
        }
        unsigned int pk[8];
        #pragma unroll
        for (int i = 0; i < 4; ++i)
            #pragma unroll
            for (int jp = 0; jp < 2; ++jp)
                pk[i*2+jp] = (unsigned int)f2b(xv[2*jp][i])
                           | ((unsigned int)f2b(xv[2*jp+1][i]) << 16);
        *(int4v*)&Xs[bufi][XSW(kgs, nbs*8)]     = *(int4v*)&pk[0];
        *(int4v*)&Xs[bufi][XSW(kgs, nbs*8 + 4)] = *(int4v*)&pk[4];
    };

    loadW(0); loadX(0);
    storeWX(0);
    __syncthreads();

    for (int ks = 0; ks < 8; ++ks) {
        int cur = ks & 1;
        if (ks < 7) { loadW(ks+1); loadX(ks+1); }

        short8 afr[4], bfr[4];
        #pragma unroll
        for (int fr = 0; fr < 4; ++fr)
            afr[fr] = *(short8*)&Ws[cur][(wr*4+fr)*512 + ln*8];
        #pragma unroll
        for (int fc = 0; fc < 4; ++fc) {
            int nn = wc*64 + fc*16 + l16;
            int2v lo = *(int2v*)&Xs[cur][XSW(2*quad,   2*nn)];
            int2v hi = *(int2v*)&Xs[cur][XSW(2*quad+1, 2*nn)];
            union { int i4[4]; short8 v; } u;
            u.i4[0] = lo.x; u.i4[1] = lo.y; u.i4[2] = hi.x; u.i4[3] = hi.y;
            bfr[fc] = u.v;
        }
        #pragma unroll
        for (int fr = 0; fr < 4; ++fr)
            #pragma unroll
            for (int fc = 0; fc < 4; ++fc)
                acc[fr][fc] = __builtin_amdgcn_mfma_f32_16x16x32_bf16(
                    afr[fr], bfr[fc], acc[fr][fc], 0, 0, 0);

        if (ks < 7) storeWX(cur ^ 1);
        __syncthreads();
    }

    #pragma unroll
    for (int fr = 0; fr < 4; ++fr) {
        #pragma unroll
        for (int r = 0; r < 4; ++r) {
            int ol = wr*64 + fr*16 + quad*4 + r;
            int o = o0 + ol;
            float vs = vsL[ol], vo = voL[ol], dcv = dcL[ol];
            const size_t orow = xbase + (size_t)o*NSP;
            #pragma unroll
            for (int fc = 0; fc < 4; ++fc) {
                int nl = wc*64 + fc*16 + l16;
                int nn = n0 + nl;
                if (nn < NSP) {
                    size_t gi = orow + nn;
                    out[gi] = (acc[fr][fc][r]*vs + vo)*(dcv + dtfL[nl]) + x[gi];
                }
            }
        }
    }
}

extern "C" void kernel_launch(void* const* d_in, const int* in_sizes, int n_in,
                              void* d_out, int out_size, void* d_ws, size_t ws_size,
                              hipStream_t stream)
{
    const float* x    = (const float*)d_in[0];
    const float* qc_w = (const float*)d_in[1];  const float* qc_bn = (const float*)d_in[2];
    const float* kc_w = (const float*)d_in[3];  const float* kc_bn = (const float*)d_in[4];
    const float* lc_bn= (const float*)d_in[5];
    const float* qf_w = (const float*)d_in[6];  const float* qf_bn = (const float*)d_in[7];
    const float* kf_w = (const float*)d_in[8];  const float* kf_bn = (const float*)d_in[9];
    const float* lf_bn= (const float*)d_in[10];
    const float* qt_w = (const float*)d_in[11]; const float* qt_bn = (const float*)d_in[12];
    const float* kt_w = (const float*)d_in[13]; const float* kt_bn = (const float*)d_in[14];
    const float* lt_bn= (const float*)d_in[15];
    const float* v_w  = (const float*)d_in[16]; const float* v_b   = (const float*)d_in[17];
    const float* v_bn = (const float*)d_in[18];
    float* ws = (float*)d_ws;
    float* out = (float*)d_out;

    int fuse_t = (ws_size >= (size_t)WS2_END * sizeof(float)) ? 1 : 0;
    int wbf    = (ws_size >= (size_t)WS3_END * sizeof(float)) ? 1 : 0;
    int newq   = (ws_size >= (size_t)WS4_END * sizeof(float)) ? 1 : 0;

    prep_kernel<<<wbf ? 33 : 25, 256, 0, stream>>>(qc_w,qc_bn,kc_w,kc_bn,lc_bn,
                                                   qf_w,qf_bn,kf_w,kf_bn,lf_bn,
                                                   qt_w,qt_bn,kt_w,kt_bn,lt_bn,
                                                   v_b,v_bn,v_w,ws);
    if (newq) {
        qv_kernel<<<2240, 512, 0, stream>>>(x, ws);
        sm_kernel<<<256, 256, 0, stream>>>(ws);
    } else {
        qkt_kernel<<<NB*NF*2, 512, 0, stream>>>(x, ws, fuse_t);
        if (fuse_t) tsm_kernel<<<NB, 256, 0, stream>>>(ws);
        else        t_kernel<<<NB*8, 256, 0, stream>>>(x, ws);
    }
    if (wbf) main_kernel<1><<<896, 256, 0, stream>>>(x, v_w, ws, out);
    else     main_kernel<0><<<896, 256, 0, stream>>>(x, v_w, ws, out);
}